// Round 8
// baseline (185.043 us; speedup 1.0000x reference)
//
#include <hip/hip_runtime.h>
#include <hip/hip_bf16.h>
#include <hip/hip_cooperative_groups.h>

namespace cg = cooperative_groups;

// ---------------------------------------------------------------------------
// MoE conv, fully fused single cooperative kernel (2 grid syncs), 256 blocks
// (1 block/CU -> co-residency guaranteed):
//   P1 (all blks): transpose 4 (b,h)-rows -> xt[b][h][g][w][ci8] bf16,
//                  + gate partial sums gpart[b][h][ci]
//   P2 (all blks): block=(cog,b): derive gates (softmax/top4) from gpart,
//                  combine W -> wc[b][p][g][co][ci8] bf16, bc[b][co];
//                  blk 255 additionally computes the aux CV loss.
//   P3 (all blks): block=(rt,b): conv = 9 shifted K=64 bf16 MFMA GEMMs,
//                  wave = 64co x 32px, 4x2 tiles (proven r5/r6 body)
// ---------------------------------------------------------------------------

typedef __attribute__((ext_vector_type(8))) short bf16x8;
typedef __attribute__((ext_vector_type(4))) float f32x4;

__device__ inline unsigned short f2bf(float f) {
  unsigned u = __builtin_bit_cast(unsigned, f);
  unsigned r = u + 0x7FFFu + ((u >> 16) & 1u);
  return (unsigned short)(r >> 16);
}

__device__ inline void softmax_top4(const float* sl, float* gv, int* ge) {
  float m = sl[0];
#pragma unroll
  for (int i = 1; i < 16; ++i) m = fmaxf(m, sl[i]);
  float p[16];
  float z = 0.f;
#pragma unroll
  for (int i = 0; i < 16; ++i) { p[i] = expf(sl[i] - m); z += p[i]; }
#pragma unroll
  for (int i = 0; i < 16; ++i) p[i] /= z;
  bool used[16];
#pragma unroll
  for (int i = 0; i < 16; ++i) used[i] = false;
  float val[4];
  for (int j = 0; j < 4; ++j) {
    int bi = 0; float bv = -1.f;
    for (int i = 0; i < 16; ++i)
      if (!used[i] && p[i] > bv) { bv = p[i]; bi = i; }
    used[bi] = true; ge[j] = bi; val[j] = bv;
  }
  float ssum = val[0] + val[1] + val[2] + val[3] + 1e-6f;
  for (int j = 0; j < 4; ++j) gv[j] = val[j] / ssum;
}

__global__ __launch_bounds__(512) void fused_kernel(
    const float* __restrict__ x, const float* __restrict__ w_gate,
    const float* __restrict__ W, const float* __restrict__ bias,
    unsigned short* __restrict__ xt, unsigned short* __restrict__ wc,
    float* __restrict__ gpart, float* __restrict__ bc,
    float* __restrict__ y, float* __restrict__ loss_out) {
  cg::grid_group grid = cg::this_grid();
  int blk = blockIdx.x;  // 0..255
  int t = threadIdx.x;   // 0..511

  __shared__ float tile[64][65];   // P1
  __shared__ float red[8][64];     // P2
  __shared__ float sgx[16][64];    // P2 (combine uses row 0; loss uses all)
  __shared__ float sl[16][16];     // P2
  __shared__ float sg[16][16];     // loss
  __shared__ float simp[16], sld[16];
  __shared__ float gsh[4];
  __shared__ int esh[4];
  __shared__ float was[2304];      // combine staging [co_l][ci][p]

  // ---------------- Phase 1: transpose + gate partials ----------------
#pragma unroll
  for (int u = 0; u < 4; ++u) {
    int bh = blk * 4 + u;
    int b = bh >> 6, h = bh & 63;
    __syncthreads();  // tile reuse guard
#pragma unroll
    for (int k = 0; k < 2; ++k) {
      int idx = t + k * 512;  // 0..1023
      int ci = idx >> 4;
      int w4 = idx & 15;
      float4 v = *(const float4*)(x + ((((size_t)b * 64 + ci) * 64 + h) * 64 + w4 * 4));
      tile[ci][w4 * 4 + 0] = v.x;
      tile[ci][w4 * 4 + 1] = v.y;
      tile[ci][w4 * 4 + 2] = v.z;
      tile[ci][w4 * 4 + 3] = v.w;
    }
    __syncthreads();
    if (t < 64) {  // gate partial: sum over w for ci=t
      float s = 0.f;
#pragma unroll
      for (int w2 = 0; w2 < 64; ++w2) s += tile[t][w2];
      gpart[(size_t)bh * 64 + t] = s;
    }
    {
      int g = t >> 6, wo = t & 63;
      bf16x8 v;
#pragma unroll
      for (int j = 0; j < 8; ++j) v[j] = (short)f2bf(tile[g * 8 + j][wo]);
      *(bf16x8*)(xt + (((size_t)bh * 8 + g) * 64 + wo) * 8) = v;
    }
  }

  grid.sync();

  // ---------------- Phase 2: gates + combine (+ loss on blk 255) ----------
  {
    int cog = blk & 15, b = blk >> 4;
    {
      int hg = t >> 6, ci = t & 63;
      float s = 0.f;
#pragma unroll
      for (int hh = 0; hh < 8; ++hh)
        s += gpart[((size_t)(b * 64 + hg * 8 + hh)) * 64 + ci];
      red[hg][ci] = s;
    }
    __syncthreads();
    if (t < 64) {
      float s = 0.f;
#pragma unroll
      for (int i = 0; i < 8; ++i) s += red[i][t];
      sgx[0][t] = s * (1.0f / 4096.0f);
    }
    __syncthreads();
    if (t < 16) {
      float acc = 0.f;
      for (int c = 0; c < 64; ++c) acc += sgx[0][c] * w_gate[c * 16 + t];
      sl[0][t] = acc;
    }
    __syncthreads();
    if (t == 0) {
      float gv[4]; int ge[4];
      softmax_top4(sl[0], gv, ge);
#pragma unroll
      for (int j = 0; j < 4; ++j) { gsh[j] = gv[j]; esh[j] = ge[j]; }
    }
    __syncthreads();
    float g0 = gsh[0], g1 = gsh[1], g2 = gsh[2], g3 = gsh[3];
    int e0 = esh[0], e1 = esh[1], e2 = esh[2], e3 = esh[3];
    if (cog == 0 && t < 64)
      bc[b * 64 + t] = g0 * bias[e0 * 64 + t] + g1 * bias[e1 * 64 + t] +
                       g2 * bias[e2 * 64 + t] + g3 * bias[e3 * 64 + t];
    const float* b0 = W + e0 * 36864 + cog * 2304;
    const float* b1 = W + e1 * 36864 + cog * 2304;
    const float* b2 = W + e2 * 36864 + cog * 2304;
    const float* b3 = W + e3 * 36864 + cog * 2304;
#pragma unroll
    for (int j = 0; j < 5; ++j) {
      int o = t + j * 512;  // coalesced
      if (o < 2304) was[o] = g0 * b0[o] + g1 * b1[o] + g2 * b2[o] + g3 * b3[o];
    }
    __syncthreads();
    if (t < 288) {
      int co_l = t & 3, gg = (t >> 2) & 7, p = t >> 5;
      bf16x8 ov;
#pragma unroll
      for (int j = 0; j < 8; ++j)
        ov[j] = (short)f2bf(was[co_l * 576 + (gg * 8 + j) * 9 + p]);
      *(bf16x8*)(wc + (size_t)b * 36864 + ((p * 8 + gg) * 64 + cog * 4 + co_l) * 8) = ov;
    }
  }

  if (blk == 255) {
    // ---- aux CV loss (serial after this block's combine; LDS reused) ----
    __syncthreads();
    for (int bb = 0; bb < 16; ++bb) {
      {
        int hg = t >> 6, ci = t & 63;
        float s = 0.f;
#pragma unroll
        for (int hh = 0; hh < 8; ++hh)
          s += gpart[((size_t)(bb * 64 + hg * 8 + hh)) * 64 + ci];
        red[hg][ci] = s;
      }
      __syncthreads();
      if (t < 64) {
        float s = 0.f;
#pragma unroll
        for (int i = 0; i < 8; ++i) s += red[i][t];
        sgx[bb][t] = s * (1.0f / 4096.0f);
      }
      __syncthreads();
    }
    if (t < 256) {
      int bb = t >> 4, e = t & 15;
      float acc = 0.f;
      for (int c = 0; c < 64; ++c) acc += sgx[bb][c] * w_gate[c * 16 + e];
      sl[bb][e] = acc;
    }
    __syncthreads();
    if (t < 16) {
      float gv[4]; int ge[4];
      softmax_top4(sl[t], gv, ge);
#pragma unroll
      for (int i = 0; i < 16; ++i) sg[t][i] = 0.f;
      for (int j = 0; j < 4; ++j) sg[t][ge[j]] = gv[j];
    }
    __syncthreads();
    if (t < 16) {
      int ee = t; float imp = 0.f, ld = 0.f;
      for (int bb = 0; bb < 16; ++bb) {
        float g = sg[bb][ee];
        imp += g;
        if (g > 0.f) ld += 1.f;
      }
      simp[ee] = imp; sld[ee] = ld;
    }
    __syncthreads();
    if (t == 0) {
      float mi = 0.f, ml = 0.f;
      for (int i = 0; i < 16; ++i) { mi += simp[i]; ml += sld[i]; }
      mi *= (1.f / 16.f); ml *= (1.f / 16.f);
      float vi = 0.f, vl = 0.f;
      for (int i = 0; i < 16; ++i) {
        float d = simp[i] - mi; vi += d * d;
        float dl = sld[i] - ml; vl += dl * dl;
      }
      vi *= (1.f / 15.f); vl *= (1.f / 15.f);  // ddof=1
      loss_out[0] = (vi / (mi * mi + 1e-10f) + vl / (ml * ml + 1e-10f)) * 0.01f;
    }
  }

  grid.sync();

  // ---------------- Phase 3: conv via 9 shifted K=64 MFMA GEMMs ----------
  {
    int rt = blk & 15;  // row-tile
    int b = blk >> 4;
    int wv = t >> 6, L = t & 63;
    int lane15 = L & 15, quad = L >> 4;
    int row = rt * 4 + (wv >> 1);
    int colbase = (wv & 1) * 32;
    const unsigned short* xtb = xt + ((size_t)b << 18);
    const unsigned short* wcb = wc + (size_t)b * 36864;
    f32x4 acc[4][2];
#pragma unroll
    for (int mt = 0; mt < 4; ++mt)
#pragma unroll
      for (int nt = 0; nt < 2; ++nt) acc[mt][nt] = (f32x4){0.f, 0.f, 0.f, 0.f};
    const bf16x8 zero = {0, 0, 0, 0, 0, 0, 0, 0};
#pragma unroll
    for (int p = 0; p < 9; ++p) {
      int dr = p / 3, dc = p % 3;
      int h = row + dr - 1;
      bool hok = (unsigned)h < 64u;
#pragma unroll
      for (int ck = 0; ck < 2; ++ck) {
        int g = ck * 4 + quad;
        bf16x8 bfr[2];
#pragma unroll
        for (int nt = 0; nt < 2; ++nt) {
          int w = colbase + nt * 16 + lane15 + dc - 1;
          bf16x8 v = zero;
          if (hok && (unsigned)w < 64u)
            v = *(const bf16x8*)(xtb + (((h << 3) + g) << 9) + (w << 3));
          bfr[nt] = v;
        }
        bf16x8 afr[4];
#pragma unroll
        for (int mt = 0; mt < 4; ++mt)
          afr[mt] = *(const bf16x8*)(wcb + ((((p << 3) + g) << 6) + mt * 16 + lane15) * 8);
#pragma unroll
        for (int mt = 0; mt < 4; ++mt)
#pragma unroll
          for (int nt = 0; nt < 2; ++nt)
            acc[mt][nt] = __builtin_amdgcn_mfma_f32_16x16x32_bf16(afr[mt], bfr[nt], acc[mt][nt], 0, 0, 0);
      }
    }
#pragma unroll
    for (int mt = 0; mt < 4; ++mt) {
#pragma unroll
      for (int r = 0; r < 4; ++r) {
        int co = mt * 16 + quad * 4 + r;
        float bv = bc[(b << 6) + co];
#pragma unroll
        for (int nt = 0; nt < 2; ++nt) {
          int w = colbase + nt * 16 + lane15;
          y[(((size_t)(b << 6) + co) << 12) + (row << 6) + w] = acc[mt][nt][r] + bv;
        }
      }
    }
  }
}

// ---------------------------------------------------------------------------
extern "C" void kernel_launch(void* const* d_in, const int* in_sizes, int n_in,
                              void* d_out, int out_size, void* d_ws, size_t ws_size,
                              hipStream_t stream) {
  const float* x = (const float*)d_in[0];       // (16,64,64,64)
  const float* w_gate = (const float*)d_in[1];  // (64,16)
  const float* W = (const float*)d_in[3];       // (16,64,64,3,3)
  const float* bias = (const float*)d_in[4];    // (16,64)
  float* out = (float*)d_out;                   // y (4194304) ++ loss (1)
  float* ws = (float*)d_ws;

  float* gpart = ws;                                   // [0, 65536) f
  float* bc = ws + 65536;                              // [65536, 66560) f
  unsigned short* wc = (unsigned short*)(ws + 66560);  // 589824 bf16
  unsigned short* xt = (unsigned short*)(ws + 361472); // 4194304 bf16
  float* loss_out = out + 4194304;

  void* args[] = {(void*)&x, (void*)&w_gate, (void*)&W, (void*)&bias,
                  (void*)&xt, (void*)&wc, (void*)&gpart, (void*)&bc,
                  (void*)&out, (void*)&loss_out};
  hipLaunchCooperativeKernel((void*)fused_kernel, dim3(256), dim3(512), args, 0,
                             stream);
}

// Round 9
// 103.833 us; speedup vs baseline: 1.7821x; 1.7821x over previous
//
#include <hip/hip_runtime.h>
#include <hip/hip_bf16.h>

// ---------------------------------------------------------------------------
// MoE conv via combined-weight trick + bf16 MFMA. 3-kernel pipeline (r6) +
// LDS-staged combined weights in the conv:
//   T transpose:    xt[b][h][g][w][ci8] (bf16) + gpart[b][h][ci]
//   C combine_gate: per-(cog,b) block re-derives gates from gpart locally
//                   (softmax/top4), emits wc[b][p][g][co][ci8] + bc[b][co];
//                   extra block column computes aux loss concurrently.
//   D conv_mfma:    stages wc[b] (72 KB) in LDS shared by 8 waves, then
//                   9 shifted K=64 GEMMs; wave = 64co x 32px, 4x2 tiles.
// Note: cooperative single-kernel fusion (r7/r8) regressed badly: VGPR spill
// to 44 regs + grid.sync cost ~80 us of stall. Do not re-fuse.
// ---------------------------------------------------------------------------

typedef __attribute__((ext_vector_type(8))) short bf16x8;
typedef __attribute__((ext_vector_type(4))) float f32x4;

__device__ inline unsigned short f2bf(float f) {
  unsigned u = __builtin_bit_cast(unsigned, f);
  unsigned r = u + 0x7FFFu + ((u >> 16) & 1u);
  return (unsigned short)(r >> 16);
}

// ---- Kernel T: xt[b][h][g][w][ci8] + gpart[b][h][ci] ----------------------
__global__ __launch_bounds__(256) void transpose_kernel(const float* __restrict__ x,
                                                        unsigned short* __restrict__ xt,
                                                        float* __restrict__ gpart) {
  int bh = blockIdx.x;  // b*64 + h
  int b = bh >> 6, h = bh & 63;
  __shared__ float tile[64][65];
  int t = threadIdx.x;
#pragma unroll
  for (int k = 0; k < 4; ++k) {
    int idx = t + k * 256;      // 0..1023
    int ci = idx >> 4;          // 0..63
    int w4 = idx & 15;          // 0..15
    float4 v = *(const float4*)(x + ((((size_t)b * 64 + ci) * 64 + h) * 64 + w4 * 4));
    tile[ci][w4 * 4 + 0] = v.x;
    tile[ci][w4 * 4 + 1] = v.y;
    tile[ci][w4 * 4 + 2] = v.z;
    tile[ci][w4 * 4 + 3] = v.w;
  }
  __syncthreads();
  if (t < 64) {  // gate partial: sum over w for ci=t
    float s = 0.f;
#pragma unroll
    for (int w2 = 0; w2 < 64; ++w2) s += tile[t][w2];
    gpart[(size_t)bh * 64 + t] = s;
  }
#pragma unroll
  for (int it = 0; it < 2; ++it) {
    int idx = t + it * 256;  // 0..511
    int g = idx >> 6;        // ci-group 0..7
    int wo = idx & 63;
    bf16x8 v;
#pragma unroll
    for (int j = 0; j < 8; ++j) v[j] = (short)f2bf(tile[g * 8 + j][wo]);
    *(bf16x8*)(xt + (((size_t)bh * 8 + g) * 64 + wo) * 8) = v;
  }
}

// ---- softmax + stable top-4 helper (single thread, 16 experts) ------------
__device__ inline void softmax_top4(const float* sl, float* gv, int* ge) {
  float m = sl[0];
#pragma unroll
  for (int i = 1; i < 16; ++i) m = fmaxf(m, sl[i]);
  float p[16];
  float z = 0.f;
#pragma unroll
  for (int i = 0; i < 16; ++i) { p[i] = expf(sl[i] - m); z += p[i]; }
#pragma unroll
  for (int i = 0; i < 16; ++i) p[i] /= z;
  bool used[16];
#pragma unroll
  for (int i = 0; i < 16; ++i) used[i] = false;
  float val[4];
  for (int j = 0; j < 4; ++j) {
    int bi = 0; float bv = -1.f;
    for (int i = 0; i < 16; ++i)
      if (!used[i] && p[i] > bv) { bv = p[i]; bi = i; }
    used[bi] = true; ge[j] = bi; val[j] = bv;
  }
  float ssum = val[0] + val[1] + val[2] + val[3] + 1e-6f;
  for (int j = 0; j < 4; ++j) gv[j] = val[j] / ssum;
}

// ---- Kernel C: fused gate + combine (+ loss in extra block column) --------
// grid (17, 16): cog 0..15 -> combine 4 co for batch b; cog==16,b==0 -> loss.
__global__ __launch_bounds__(256) void combine_gate_kernel(const float* __restrict__ gpart,
                                                           const float* __restrict__ w_gate,
                                                           const float* __restrict__ W,
                                                           const float* __restrict__ bias,
                                                           unsigned short* __restrict__ wc,
                                                           float* __restrict__ bc,
                                                           float* __restrict__ loss_out) {
  int cog = blockIdx.x;  // 0..16
  int b = blockIdx.y;
  int t = threadIdx.x;

  if (cog == 16) {  // ---- loss block (one per grid) ----
    if (b != 0) return;
    __shared__ float red[4][64];
    __shared__ float sgx[16][64];
    __shared__ float sl[16][16];
    __shared__ float sg[16][16];
    __shared__ float simp[16], sld[16];
    int hg = t >> 6, ci = t & 63;
    for (int bb = 0; bb < 16; ++bb) {
      float s = 0.f;
#pragma unroll
      for (int hh = 0; hh < 16; ++hh)
        s += gpart[((size_t)(bb * 64 + hg * 16 + hh)) * 64 + ci];
      red[hg][ci] = s;
      __syncthreads();
      if (t < 64) sgx[bb][t] = (red[0][t] + red[1][t] + red[2][t] + red[3][t]) * (1.0f / 4096.0f);
      __syncthreads();
    }
    {
      int bb = t >> 4, e = t & 15;
      float acc = 0.f;
      for (int c = 0; c < 64; ++c) acc += sgx[bb][c] * w_gate[c * 16 + e];
      sl[bb][e] = acc;
    }
    __syncthreads();
    if (t < 16) {
      float gv[4]; int ge[4];
      softmax_top4(sl[t], gv, ge);
#pragma unroll
      for (int i = 0; i < 16; ++i) sg[t][i] = 0.f;
      for (int j = 0; j < 4; ++j) sg[t][ge[j]] = gv[j];
    }
    __syncthreads();
    if (t < 16) {
      int ee = t; float imp = 0.f, ld = 0.f;
      for (int bb = 0; bb < 16; ++bb) {
        float g = sg[bb][ee];
        imp += g;
        if (g > 0.f) ld += 1.f;
      }
      simp[ee] = imp; sld[ee] = ld;
    }
    __syncthreads();
    if (t == 0) {
      float mi = 0.f, ml = 0.f;
      for (int i = 0; i < 16; ++i) { mi += simp[i]; ml += sld[i]; }
      mi *= (1.f / 16.f); ml *= (1.f / 16.f);
      float vi = 0.f, vl = 0.f;
      for (int i = 0; i < 16; ++i) {
        float d = simp[i] - mi; vi += d * d;
        float dl = sld[i] - ml; vl += dl * dl;
      }
      vi *= (1.f / 15.f); vl *= (1.f / 15.f);  // ddof=1
      loss_out[0] = (vi / (mi * mi + 1e-10f) + vl / (ml * ml + 1e-10f)) * 0.01f;
    }
    return;
  }

  // ---- combine block: derive this b's gates locally, then combine slab ----
  __shared__ float red[4][64];
  __shared__ float sgx[64];
  __shared__ float sl[16];
  __shared__ float g[4];
  __shared__ int e[4];
  __shared__ float was[2304];  // [co_l][ci][p] in W-native order
  {
    int hg = t >> 6, ci = t & 63;
    float s = 0.f;
#pragma unroll
    for (int hh = 0; hh < 16; ++hh)
      s += gpart[((size_t)(b * 64 + hg * 16 + hh)) * 64 + ci];
    red[hg][ci] = s;
  }
  __syncthreads();
  if (t < 64) sgx[t] = (red[0][t] + red[1][t] + red[2][t] + red[3][t]) * (1.0f / 4096.0f);
  __syncthreads();
  if (t < 16) {
    float acc = 0.f;
    for (int c = 0; c < 64; ++c) acc += sgx[c] * w_gate[c * 16 + t];
    sl[t] = acc;
  }
  __syncthreads();
  if (t == 0) {
    float gv[4]; int ge[4];
    softmax_top4(sl, gv, ge);
#pragma unroll
    for (int j = 0; j < 4; ++j) { g[j] = gv[j]; e[j] = ge[j]; }
  }
  __syncthreads();
  float g0 = g[0], g1 = g[1], g2 = g[2], g3 = g[3];
  int e0 = e[0], e1 = e[1], e2 = e[2], e3 = e[3];
  if (cog == 0 && t < 64)
    bc[b * 64 + t] = g0 * bias[e0 * 64 + t] + g1 * bias[e1 * 64 + t] +
                     g2 * bias[e2 * 64 + t] + g3 * bias[e3 * 64 + t];
  const float* b0 = W + e0 * 36864 + cog * 2304;
  const float* b1 = W + e1 * 36864 + cog * 2304;
  const float* b2 = W + e2 * 36864 + cog * 2304;
  const float* b3 = W + e3 * 36864 + cog * 2304;
  float acc[9];
#pragma unroll
  for (int j = 0; j < 9; ++j) {
    int o = t + j * 256;  // coalesced
    acc[j] = g0 * b0[o] + g1 * b1[o] + g2 * b2[o] + g3 * b3[o];
  }
#pragma unroll
  for (int j = 0; j < 9; ++j) was[t + j * 256] = acc[j];
  __syncthreads();
  for (int v = t; v < 288; v += 256) {
    int co_l = v & 3, gg = (v >> 2) & 7, p = v >> 5;
    bf16x8 ov;
#pragma unroll
    for (int j = 0; j < 8; ++j)
      ov[j] = (short)f2bf(was[co_l * 576 + (gg * 8 + j) * 9 + p]);
    *(bf16x8*)(wc + (size_t)b * 36864 + ((p * 8 + gg) * 64 + cog * 4 + co_l) * 8) = ov;
  }
}

// ---- Kernel D: conv via 9 shifted K=64 bf16 MFMA GEMMs --------------------
// grid (16 row-tiles, 16 b) = 256 blocks; 512 threads = 8 waves;
// wc[b] slab (72 KB) staged in LDS once, shared by all 8 waves (A-frags via
// ds_read_b128); B-frags (xt) from global/L2; wave = 64co x 32px, 4x2 tiles.
__global__ __launch_bounds__(512, 2) void conv_mfma(const unsigned short* __restrict__ xt,
                                                    const unsigned short* __restrict__ wc,
                                                    const float* __restrict__ bc,
                                                    float* __restrict__ y) {
  __shared__ __align__(16) unsigned short wcs[36864];  // 72 KB
  int rt = blockIdx.x;  // 0..15
  int b = blockIdx.y;   // 0..15
  int tid = threadIdx.x;
  const unsigned short* wcb = wc + (size_t)b * 36864;
  // stage combined-weight slab: 4608 x 16B, coalesced
#pragma unroll
  for (int i = 0; i < 9; ++i)
    ((bf16x8*)wcs)[tid + i * 512] = ((const bf16x8*)wcb)[tid + i * 512];
  __syncthreads();

  int wv = tid >> 6, L = tid & 63;
  int lane15 = L & 15, quad = L >> 4;
  int row = rt * 4 + (wv >> 1);
  int colbase = (wv & 1) * 32;
  const unsigned short* xtb = xt + ((size_t)b << 18);  // 64h*8g*64w*8
  f32x4 acc[4][2];
#pragma unroll
  for (int mt = 0; mt < 4; ++mt)
#pragma unroll
    for (int nt = 0; nt < 2; ++nt) acc[mt][nt] = (f32x4){0.f, 0.f, 0.f, 0.f};
  const bf16x8 zero = {0, 0, 0, 0, 0, 0, 0, 0};
#pragma unroll
  for (int p = 0; p < 9; ++p) {
    int dr = p / 3, dc = p % 3;
    int h = row + dr - 1;
    bool hok = (unsigned)h < 64u;
#pragma unroll
    for (int ck = 0; ck < 2; ++ck) {
      int g = ck * 4 + quad;
      bf16x8 bfr[2];
#pragma unroll
      for (int nt = 0; nt < 2; ++nt) {
        int w = colbase + nt * 16 + lane15 + dc - 1;
        bf16x8 v = zero;
        if (hok && (unsigned)w < 64u)
          v = *(const bf16x8*)(xtb + (((h << 3) + g) << 9) + (w << 3));
        bfr[nt] = v;
      }
      bf16x8 afr[4];
#pragma unroll
      for (int mt = 0; mt < 4; ++mt)
        afr[mt] = *(const bf16x8*)(wcs + ((((p << 3) + g) << 6) + mt * 16 + lane15) * 8);
#pragma unroll
      for (int mt = 0; mt < 4; ++mt)
#pragma unroll
        for (int nt = 0; nt < 2; ++nt)
          acc[mt][nt] = __builtin_amdgcn_mfma_f32_16x16x32_bf16(afr[mt], bfr[nt], acc[mt][nt], 0, 0, 0);
    }
  }
#pragma unroll
  for (int mt = 0; mt < 4; ++mt) {
#pragma unroll
    for (int r = 0; r < 4; ++r) {
      int co = mt * 16 + quad * 4 + r;
      float bv = bc[(b << 6) + co];
#pragma unroll
      for (int nt = 0; nt < 2; ++nt) {
        int w = colbase + nt * 16 + lane15;
        y[(((size_t)(b << 6) + co) << 12) + (row << 6) + w] = acc[mt][nt][r] + bv;
      }
    }
  }
}

// ---------------------------------------------------------------------------
extern "C" void kernel_launch(void* const* d_in, const int* in_sizes, int n_in,
                              void* d_out, int out_size, void* d_ws, size_t ws_size,
                              hipStream_t stream) {
  const float* x = (const float*)d_in[0];       // (16,64,64,64)
  const float* w_gate = (const float*)d_in[1];  // (64,16)
  const float* W = (const float*)d_in[3];       // (16,64,64,3,3)
  const float* bias = (const float*)d_in[4];    // (16,64)
  float* out = (float*)d_out;                   // y (4194304) ++ loss (1)
  float* ws = (float*)d_ws;

  float* gpart = ws;                                     // [0, 65536) f
  float* bc = ws + 65536;                                // [65536, 66560) f
  unsigned short* wc = (unsigned short*)(ws + 66560);    // 589824 bf16
  unsigned short* xt = (unsigned short*)(ws + 361472);   // 4194304 bf16

  transpose_kernel<<<1024, 256, 0, stream>>>(x, xt, gpart);
  {
    dim3 grid(17, 16);
    combine_gate_kernel<<<grid, 256, 0, stream>>>(gpart, w_gate, W, bias, wc, bc,
                                                  out + 4194304);
  }
  {
    dim3 grid(16, 16);
    conv_mfma<<<grid, 512, 0, stream>>>(xt, wc, bc, out);
  }
}